// Round 2
// baseline (229.383 us; speedup 1.0000x reference)
//
#include <hip/hip_runtime.h>

// GNN_Critic: 2-layer SAGEConv (F: 1 -> 16 -> 1) + global_add_pool.
//
// Round-6: round-5's occupancy-doubling null proved the bin passes are
// scattered-gather THROUGHPUT-bound (per-lane TA/cacheline addressing), not
// latency-bound. This round removes all per-lane global addressing from the
// hot loops:
//   1. partition by dst-part (16 parts, unchanged)
//   2. NEW subpart pass: re-bucket each part's edges by src-bucket of 8192
//      (25 buckets) -> pairsC[(part,sb)] cells, same LDS-ring machinery
//   3. bin passes: one block per (part,sb) cell; stage the 32KB x/pv slice
//      into LDS (coalesced), per-edge gather becomes ds_read (LDS native
//      per-lane addressing); bins flush via coalesced global atomicAdd into
//      packed acc1[N]/acc2[N] (integer adds -> order-independent, bit-exact)
//   4. node passes read acc[N] directly (slab round-trips removed; the
//      added pairsC round-trip ~= removed slab traffic, so streaming flat)

#define PP        16            // dst parts
#define BLK       1024
#define SCAP      1024u         // partition ring capacity (u32)
#define SMASK     1023u
#define TILE      (BLK * 4)     // 4096 edges per partition block
#define SBW       8192          // src-bucket width (32KB of f32 in LDS)
#define SBSH      13
#define SC2       512u          // subpart ring capacity
#define SM2       511u
#define CNT_ONE   (1u << 25)    // pass-1 count field bits [31:25]
#define FX_BIAS   131072        // 2^17 per-add bias keeps sum field positive
#define SCALE     4096.0f       // 2^12 fixed-point scale
#define INV_SCALE (1.0f / 4096.0f)

// ---------------------------------------------------------------------------
// Counting partition by dst-part (unchanged from round-4).
__global__ __launch_bounds__(BLK) void partition_kernel(
    const int* __restrict__ ei, unsigned* __restrict__ pairs,
    unsigned* __restrict__ tails, int E, int bins, unsigned Mdiv, int cap) {
    extern __shared__ unsigned buf[];                 // [PP][SCAP] = 64 KB
    __shared__ unsigned cnt[PP], base[PP], fq[PP], gb[PP];
    const int tid = threadIdx.x;
    if (tid < PP) { cnt[tid] = 0; base[tid] = 0; }
    __syncthreads();

    int b0 = blockIdx.x * TILE;
    int e0 = b0 + tid * 4;
    int nv = E - e0; nv = nv < 0 ? 0 : (nv > 4 ? 4 : nv);
    int srcv[4], dstv[4];
    if (nv == 4 && ((E & 3) == 0)) {
        int4 s = *(const int4*)(ei + e0);
        int4 d = *(const int4*)(ei + E + e0);
        srcv[0] = s.x; srcv[1] = s.y; srcv[2] = s.z; srcv[3] = s.w;
        dstv[0] = d.x; dstv[1] = d.y; dstv[2] = d.z; dstv[3] = d.w;
    } else {
        for (int j = 0; j < nv; ++j) { srcv[j] = ei[e0 + j]; dstv[j] = ei[E + e0 + j]; }
    }
    unsigned w[4]; int part[4]; bool pend[4];
    for (int j = 0; j < 4; ++j) {
        pend[j] = (j < nv);
        if (pend[j]) {
            unsigned dst = (unsigned)dstv[j];
            unsigned pt = (unsigned)(((unsigned long long)dst * Mdiv) >> 32);
            int ld = (int)dst - (int)pt * bins;
            while (ld >= bins) { ld -= bins; ++pt; }
            while (ld < 0)     { ld += bins; --pt; }
            part[j] = (int)pt;
            w[j] = ((unsigned)srcv[j] << 14) | (unsigned)ld;
        }
    }
    for (int j = 0; j < 4; ++j) {
        if (pend[j]) {
            unsigned slot = atomicAdd(&cnt[part[j]], 1u);
            if (slot - base[part[j]] < SCAP) {
                buf[part[j] * SCAP + (slot & SMASK)] = w[j]; pend[j] = false;
            } else atomicSub(&cnt[part[j]], 1u);
        }
    }
    int npend = __syncthreads_count((int)(pend[0] | pend[1] | pend[2] | pend[3]));
    while (npend > 0) {
        if (tid < PP) {
            unsigned avail = cnt[tid] - base[tid];
            unsigned f = avail & ~511u;
            fq[tid] = f;
            if (f) gb[tid] = atomicAdd(&tails[tid], f);
        }
        __syncthreads();
        {
            int wv = tid >> 6, lane = tid & 63;
            unsigned f = fq[wv];
            if (f) {
                unsigned g0 = gb[wv], bs = base[wv];
                unsigned mx = (g0 + f <= (unsigned)cap) ? f : ((unsigned)cap > g0 ? (unsigned)cap - g0 : 0u);
                unsigned* dp = pairs + (size_t)wv * cap + g0;
                for (unsigned jj = lane; jj < mx; jj += 64)
                    dp[jj] = buf[wv * SCAP + ((bs + jj) & SMASK)];
            }
        }
        __syncthreads();
        if (tid < PP) base[tid] += fq[tid];
        __syncthreads();
        for (int j = 0; j < 4; ++j) {
            if (pend[j]) {
                unsigned slot = atomicAdd(&cnt[part[j]], 1u);
                if (slot - base[part[j]] < SCAP) {
                    buf[part[j] * SCAP + (slot & SMASK)] = w[j]; pend[j] = false;
                } else atomicSub(&cnt[part[j]], 1u);
            }
        }
        npend = __syncthreads_count((int)(pend[0] | pend[1] | pend[2] | pend[3]));
    }
    if (tid < PP) {
        unsigned avail = cnt[tid] - base[tid];
        fq[tid] = avail;
        if (avail) gb[tid] = atomicAdd(&tails[tid], avail);
    }
    __syncthreads();
    {
        int wv = tid >> 6, lane = tid & 63;
        unsigned f = fq[wv];
        if (f) {
            unsigned g0 = gb[wv], bs = base[wv];
            unsigned mx = (g0 + f <= (unsigned)cap) ? f : ((unsigned)cap > g0 ? (unsigned)cap - g0 : 0u);
            unsigned* dp = pairs + (size_t)wv * cap + g0;
            for (unsigned jj = lane; jj < mx; jj += 64)
                dp[jj] = buf[wv * SCAP + ((bs + jj) & SMASK)];
        }
    }
}

// ---------------------------------------------------------------------------
// Second-level partition: re-bucket part p's list by src-bucket (NSB rings).
// word in : src(18) << 14 | ld(14)
// word out: lsrc(13) << 14 | ld(14),  cell = p*NSB + (src >> SBSH)
__global__ __launch_bounds__(BLK) void subpart_kernel(
    const unsigned* __restrict__ pairsB, const unsigned* __restrict__ tails,
    unsigned* __restrict__ pairsC, unsigned* __restrict__ tails2,
    int NSB, int cap, int capSB) {
    extern __shared__ unsigned buf[];                 // [NSB][SC2]
    __shared__ unsigned cnt[32], base[32], fq[32], gb[32];
    const int tid = threadIdx.x;
    const int p = blockIdx.x & (PP - 1);
    const int c = blockIdx.x >> 4;                    // 16 chunks per part
    if (tid < NSB) { cnt[tid] = 0; base[tid] = 0; }
    __syncthreads();
    int len = (int)tails[p]; if (len > cap) len = cap;
    int st = (int)((long long)len * c / 16);
    int en = (int)((long long)len * (c + 1) / 16);
    const unsigned* bp = pairsB + (size_t)p * cap;
    unsigned* cellbase = pairsC + (size_t)p * NSB * capSB;
    unsigned* t2 = tails2 + (size_t)p * NSB;

    for (int e0 = st; e0 < en; e0 += BLK * 4) {
        unsigned w[4]; int sb[4]; bool pend[4];
        for (int j = 0; j < 4; ++j) {
            int e = e0 + tid + j * BLK;
            pend[j] = e < en;
            if (pend[j]) {
                unsigned wv = bp[e];
                unsigned src = wv >> 14;
                sb[j] = (int)(src >> SBSH);
                w[j] = ((src & (SBW - 1u)) << 14) | (wv & 16383u);
            }
        }
        for (int j = 0; j < 4; ++j) {
            if (pend[j]) {
                unsigned slot = atomicAdd(&cnt[sb[j]], 1u);
                if (slot - base[sb[j]] < SC2) {
                    buf[sb[j] * SC2 + (slot & SM2)] = w[j]; pend[j] = false;
                } else atomicSub(&cnt[sb[j]], 1u);
            }
        }
        int npend = __syncthreads_count((int)(pend[0] | pend[1] | pend[2] | pend[3]));
        while (npend > 0) {
            if (tid < NSB) {
                unsigned avail = cnt[tid] - base[tid];
                unsigned f = avail & ~255u;
                fq[tid] = f;
                if (f) gb[tid] = atomicAdd(&t2[tid], f);
            }
            __syncthreads();
            for (int r = tid >> 6; r < NSB; r += 16) {
                int lane = tid & 63;
                unsigned f = fq[r];
                if (f) {
                    unsigned g0 = gb[r], bs = base[r];
                    unsigned mx = (g0 + f <= (unsigned)capSB) ? f : ((unsigned)capSB > g0 ? (unsigned)capSB - g0 : 0u);
                    unsigned* dp = cellbase + (size_t)r * capSB + g0;
                    for (unsigned jj = lane; jj < mx; jj += 64)
                        dp[jj] = buf[r * SC2 + ((bs + jj) & SM2)];
                }
            }
            __syncthreads();
            if (tid < NSB) base[tid] += fq[tid];
            __syncthreads();
            for (int j = 0; j < 4; ++j) {
                if (pend[j]) {
                    unsigned slot = atomicAdd(&cnt[sb[j]], 1u);
                    if (slot - base[sb[j]] < SC2) {
                        buf[sb[j] * SC2 + (slot & SM2)] = w[j]; pend[j] = false;
                    } else atomicSub(&cnt[sb[j]], 1u);
                }
            }
            npend = __syncthreads_count((int)(pend[0] | pend[1] | pend[2] | pend[3]));
        }
    }
    // final drain
    if (tid < NSB) {
        unsigned avail = cnt[tid] - base[tid];
        fq[tid] = avail;
        if (avail) gb[tid] = atomicAdd(&t2[tid], avail);
    }
    __syncthreads();
    for (int r = tid >> 6; r < NSB; r += 16) {
        int lane = tid & 63;
        unsigned f = fq[r];
        if (f) {
            unsigned g0 = gb[r], bs = base[r];
            unsigned mx = (g0 + f <= (unsigned)capSB) ? f : ((unsigned)capSB > g0 ? (unsigned)capSB - g0 : 0u);
            unsigned* dp = cellbase + (size_t)r * capSB + g0;
            for (unsigned jj = lane; jj < mx; jj += 64)
                dp[jj] = buf[r * SC2 + ((bs + jj) & SM2)];
        }
    }
}

// ---------------------------------------------------------------------------
// Bin pass 1: one block per (part, src-bucket) cell. x slice staged in LDS;
// bins in LDS; flush via coalesced global atomicAdd into packed acc1[N].
__global__ __launch_bounds__(BLK) void bin1_kernel(
    const unsigned* __restrict__ pairsC, const unsigned* __restrict__ tails2,
    const float* __restrict__ x, unsigned* __restrict__ acc1,
    int N, int bins, int NSB, int capSB) {
    extern __shared__ unsigned sm[];
    float* xs = (float*)sm;                  // [SBW]
    unsigned* sbn = sm + SBW;                // [bins]
    const int tid = threadIdx.x;
    const int cell = blockIdx.x;
    const int p = cell / NSB;
    const int sbk = cell - p * NSB;
    const int n0 = sbk << SBSH;
    int nn = N - n0; if (nn > SBW) nn = SBW;
    for (int j = tid; j < nn; j += BLK) xs[j] = x[n0 + j];
    for (int j = tid; j < bins; j += BLK) sbn[j] = 0;
    __syncthreads();
    int len = (int)tails2[cell]; if (len > capSB) len = capSB;
    const unsigned* bp = pairsC + (size_t)cell * capSB;
    int len4 = len & ~3;
    const uint4* bp4 = (const uint4*)bp;
    for (int e = tid; e < (len4 >> 2); e += BLK) {
        uint4 wq = bp4[e];
        atomicAdd(&sbn[wq.x & 16383u],
                  CNT_ONE + (unsigned)((int)rintf(xs[wq.x >> 14] * SCALE) + FX_BIAS));
        atomicAdd(&sbn[wq.y & 16383u],
                  CNT_ONE + (unsigned)((int)rintf(xs[wq.y >> 14] * SCALE) + FX_BIAS));
        atomicAdd(&sbn[wq.z & 16383u],
                  CNT_ONE + (unsigned)((int)rintf(xs[wq.z >> 14] * SCALE) + FX_BIAS));
        atomicAdd(&sbn[wq.w & 16383u],
                  CNT_ONE + (unsigned)((int)rintf(xs[wq.w >> 14] * SCALE) + FX_BIAS));
    }
    for (int e = len4 + tid; e < len; e += BLK) {
        unsigned wv = bp[e];
        atomicAdd(&sbn[wv & 16383u],
                  CNT_ONE + (unsigned)((int)rintf(xs[wv >> 14] * SCALE) + FX_BIAS));
    }
    __syncthreads();
    unsigned* dst = acc1 + (size_t)p * bins;
    int nb = N - p * bins; if (nb > bins) nb = bins;
    for (int j = tid; j < nb; j += BLK) {
        unsigned v = sbn[j];
        if (v) atomicAdd(&dst[j], v);
    }
}

// ---------------------------------------------------------------------------
// Bin pass 2: same structure, pv slice in LDS, signed i32 into acc2[N].
__global__ __launch_bounds__(BLK) void bin2_kernel(
    const unsigned* __restrict__ pairsC, const unsigned* __restrict__ tails2,
    const float* __restrict__ pv, int* __restrict__ acc2,
    int N, int bins, int NSB, int capSB) {
    extern __shared__ unsigned sm[];
    float* ps = (float*)sm;                  // [SBW]
    int* sbi = (int*)(sm + SBW);             // [bins]
    const int tid = threadIdx.x;
    const int cell = blockIdx.x;
    const int p = cell / NSB;
    const int sbk = cell - p * NSB;
    const int n0 = sbk << SBSH;
    int nn = N - n0; if (nn > SBW) nn = SBW;
    for (int j = tid; j < nn; j += BLK) ps[j] = pv[n0 + j];
    for (int j = tid; j < bins; j += BLK) sbi[j] = 0;
    __syncthreads();
    int len = (int)tails2[cell]; if (len > capSB) len = capSB;
    const unsigned* bp = pairsC + (size_t)cell * capSB;
    int len4 = len & ~3;
    const uint4* bp4 = (const uint4*)bp;
    for (int e = tid; e < (len4 >> 2); e += BLK) {
        uint4 wq = bp4[e];
        atomicAdd(&sbi[wq.x & 16383u], (int)rintf(ps[wq.x >> 14] * SCALE));
        atomicAdd(&sbi[wq.y & 16383u], (int)rintf(ps[wq.y >> 14] * SCALE));
        atomicAdd(&sbi[wq.z & 16383u], (int)rintf(ps[wq.z >> 14] * SCALE));
        atomicAdd(&sbi[wq.w & 16383u], (int)rintf(ps[wq.w >> 14] * SCALE));
    }
    for (int e = len4 + tid; e < len; e += BLK) {
        unsigned wv = bp[e];
        atomicAdd(&sbi[wv & 16383u], (int)rintf(ps[wv >> 14] * SCALE));
    }
    __syncthreads();
    int* dst = acc2 + (size_t)p * bins;
    int nb = N - p * bins; if (nb > bins) nb = bins;
    for (int j = tid; j < nb; j += BLK) {
        int v = sbi[j];
        if (v) atomicAdd(&dst[j], v);
    }
}

// ---------------------------------------------------------------------------
// Node pass 1: acc1[n] -> (deg, sum1); h = relu(mean*W1l + b1 + x*W1r);
// p = h.W2l, q = h.W2r.
__global__ void node_pass1_kernel(const float* __restrict__ x,
                                  const unsigned* __restrict__ acc1,
                                  const float* __restrict__ W1l,
                                  const float* __restrict__ b1,
                                  const float* __restrict__ W1r,
                                  const float* __restrict__ W2l,
                                  const float* __restrict__ W2r,
                                  float* __restrict__ deg_out,
                                  float* __restrict__ pv,
                                  float* __restrict__ qv,
                                  int N) {
    __shared__ float s_w1l[16], s_b1[16], s_w1r[16], s_w2l[16], s_w2r[16];
    if (threadIdx.x < 16) {
        s_w1l[threadIdx.x] = W1l[threadIdx.x];
        s_b1[threadIdx.x]  = b1[threadIdx.x];
        s_w1r[threadIdx.x] = W1r[threadIdx.x];
        s_w2l[threadIdx.x] = W2l[threadIdx.x];
        s_w2r[threadIdx.x] = W2r[threadIdx.x];
    }
    __syncthreads();
    int n = blockIdx.x * blockDim.x + threadIdx.x;
    if (n >= N) return;

    unsigned w = acc1[n];
    unsigned cnt = w >> 25;
    unsigned fx  = w & (CNT_ONE - 1);
    float dg  = (float)cnt;
    float sum = (float)(int)(fx - cnt * (unsigned)FX_BIAS) * INV_SCALE;
    float m   = sum / fmaxf(dg, 1.0f);

    float xv = x[n];
    float pa = 0.0f, qa = 0.0f;
#pragma unroll
    for (int f = 0; f < 16; ++f) {
        float h = fmaf(m, s_w1l[f], fmaf(xv, s_w1r[f], s_b1[f]));
        h = fmaxf(h, 0.0f);
        pa = fmaf(h, s_w2l[f], pa);
        qa = fmaf(h, s_w2r[f], qa);
    }
    deg_out[n] = dg;
    pv[n] = pa;
    qv[n] = qa;
}

// ---------------------------------------------------------------------------
// Node pass 2 + pool: h2 = acc2[n]/max(deg,1) + b2 + q; out[batch[n]] += h2.
__global__ void node_pass2_kernel(const int* __restrict__ acc2,
                                  const float* __restrict__ deg,
                                  const float* __restrict__ qv,
                                  const float* __restrict__ b2,
                                  const int* __restrict__ batch,
                                  float* __restrict__ out,
                                  int N) {
    int i = blockIdx.x * blockDim.x + threadIdx.x;
    float b2v = b2[0];
    float val = 0.0f;
    int g;
    if (i < N) {
        float s2 = (float)acc2[i] * INV_SCALE;
        val = s2 / fmaxf(deg[i], 1.0f) + b2v + qv[i];
        g = batch[i];
    } else {
        g = batch[N - 1];  // pad lanes contribute 0 to a valid graph id
    }
    int g0 = __shfl(g, 0);
    unsigned long long same = __ballot(g == g0);
    if (same == ~0ULL) {
        for (int off = 32; off > 0; off >>= 1) val += __shfl_down(val, off);
        if ((threadIdx.x & 63) == 0) atomicAdd(&out[g0], val);
    } else {
        atomicAdd(&out[g], val);
    }
}

// ---------------------------------------------------------------------------
extern "C" void kernel_launch(void* const* d_in, const int* in_sizes, int n_in,
                              void* d_out, int out_size, void* d_ws, size_t ws_size,
                              hipStream_t stream) {
    const float* x     = (const float*)d_in[0];
    const int*   ei    = (const int*)d_in[1];   // [2, E] flat: src then dst
    const int*   batch = (const int*)d_in[2];
    const float* W1l = (const float*)d_in[4];
    const float* b1  = (const float*)d_in[5];
    const float* W1r = (const float*)d_in[6];
    const float* W2l = (const float*)d_in[7];
    const float* b2  = (const float*)d_in[8];
    const float* W2r = (const float*)d_in[9];

    const int N = in_sizes[0];        // 200000
    const int E = in_sizes[1] / 2;    // 6400000
    float* out = (float*)d_out;       // [512]

    const int bins = (N + PP - 1) / PP;                       // 12500
    const int NSB  = (N + SBW - 1) / SBW;                     // 25
    const unsigned Mdiv =
        (unsigned)(((1ULL << 32) + (unsigned)bins - 1) / (unsigned)bins);
    const int EperP = E / PP;
    int cap = ((EperP + EperP / 32 + 4096) + 1023) & ~1023;   // ~20-sigma margin
    const int meanSB = E / (PP * NSB);                        // 16000
    int capSB = ((meanSB + meanSB / 4 + 2048) + 1023) & ~1023;

    // workspace (u32 words):
    // pairsB[PP][cap] | pairsC[PP*NSB][capSB] | acc1[N] | acc2[N] |
    // tails[PP] | tails2[PP*NSB] | deg,pv,qv (f32)
    unsigned* pairsB = (unsigned*)d_ws;
    unsigned* pairsC = pairsB + (size_t)PP * cap;
    unsigned* acc1   = pairsC + (size_t)PP * NSB * capSB;
    int*      acc2   = (int*)(acc1 + N);
    unsigned* tails  = (unsigned*)(acc2 + N);
    unsigned* tails2 = tails + PP;
    float* deg = (float*)(tails2 + (size_t)PP * NSB);
    float* pv  = deg + N;
    float* qv  = pv + N;

    hipMemsetAsync(d_out, 0, (size_t)out_size * sizeof(float), stream);
    // acc1 | acc2 | tails | tails2 are contiguous: single clear
    hipMemsetAsync(acc1, 0, (size_t)(2 * N + PP + PP * NSB) * 4, stream);

    const int partShmem = PP * (int)SCAP * 4;           // 65536 B
    const int subShmem  = NSB * (int)SC2 * 4;           // 51200 B
    const int binShmem  = SBW * 4 + bins * 4;           // 82768 B
    hipFuncSetAttribute((const void*)partition_kernel,
                        hipFuncAttributeMaxDynamicSharedMemorySize, partShmem);
    hipFuncSetAttribute((const void*)subpart_kernel,
                        hipFuncAttributeMaxDynamicSharedMemorySize, subShmem);
    hipFuncSetAttribute((const void*)bin1_kernel,
                        hipFuncAttributeMaxDynamicSharedMemorySize, binShmem);
    hipFuncSetAttribute((const void*)bin2_kernel,
                        hipFuncAttributeMaxDynamicSharedMemorySize, binShmem);

    int partBlocks = (E + TILE - 1) / TILE;     // 1563
    const int NB = 256;
    int node_blocks = (N + NB - 1) / NB;

    partition_kernel<<<partBlocks, BLK, partShmem, stream>>>(ei, pairsB, tails,
                                                             E, bins, Mdiv, cap);
    subpart_kernel<<<PP * 16, BLK, subShmem, stream>>>(pairsB, tails, pairsC,
                                                       tails2, NSB, cap, capSB);
    bin1_kernel<<<PP * NSB, BLK, binShmem, stream>>>(pairsC, tails2, x, acc1,
                                                     N, bins, NSB, capSB);
    node_pass1_kernel<<<node_blocks, NB, 0, stream>>>(x, acc1, W1l, b1, W1r,
                                                      W2l, W2r, deg, pv, qv, N);
    bin2_kernel<<<PP * NSB, BLK, binShmem, stream>>>(pairsC, tails2, pv, acc2,
                                                     N, bins, NSB, capSB);
    node_pass2_kernel<<<node_blocks, NB, 0, stream>>>(acc2, deg, qv, b2, batch,
                                                      out, N);
}